// Round 11
// baseline (800.714 us; speedup 1.0000x reference)
//
#include <hip/hip_runtime.h>

#define BATCH 4096
typedef unsigned short u16_t;

// ---- par sub-offsets (floats) ----
#define P_SWM   0
#define P_SWME  304
#define P_WP    608
#define P_WPE   969
#define P_GL    1330
#define P_GLVL  1349
#define P_CMT   1368
#define P_SC2   1392
#define P_SH2   1424
#define P_SC4   1456
#define P_SH4   1584
// par total 1712, reserve 2048

// ---- workspace layout (float offsets) ----
#define OFF_PAR 0L
#define OFF_B2F 2048L      // bf16 frag conv2 W (32x32): [pl2][s9][ln64][j8] = 9216 u16
#define OFF_B3F 6656L      // bf16 frag conv3 W (16x16): [pl2][nt4][tap25][ln64][j8] = 102400 u16
#define OFF_B4F 57856L     // bf16 frag conv4 W (16x16): [pl2][nt8][ks50][ln64][j8] = 409600 u16
#define OFF_DYN 262656L    // then per chunk: h2[chunk*6272 u32]

typedef __attribute__((ext_vector_type(8))) short short8;
typedef __attribute__((ext_vector_type(16))) float f32x16;
typedef __attribute__((ext_vector_type(4))) float f32x4;
#define MFMA(a, b, c) __builtin_amdgcn_mfma_f32_32x32x16_bf16(a, b, c, 0, 0, 0)
#define MFMA16(a, b, c) __builtin_amdgcn_mfma_f32_16x16x32_bf16(a, b, c, 0, 0, 0)

// byte-select: build (w1.lo16<<16)|w0.lo16 and (w1.hi16<<16)|w0.hi16
#define PERM_HI(w1, w0) __builtin_amdgcn_perm((w1), (w0), 0x05040100u)
#define PERM_LO(w1, w0) __builtin_amdgcn_perm((w1), (w0), 0x07060302u)

union U8 { unsigned u[4]; short8 v; };
union A4 { f32x4 v; float f[4]; };

__device__ __forceinline__ float sigmoidf_(float x) {
    return 1.0f / (1.0f + __expf(-x));
}
__device__ __forceinline__ float softplusf_(float x) { return log1pf(__expf(x)); }

// split fp32 -> packed (hi trunc-bf16 in low16, lo rne-bf16 of residual in high16)
__device__ __forceinline__ unsigned splitpack(float f) {
    unsigned u = __float_as_uint(f);
    float rsd = f - __uint_as_float(u & 0xFFFF0000u);
    unsigned ur = __float_as_uint(rsd);
    ur = ur + 0x7FFFu + ((ur >> 16) & 1u);
    return (u >> 16) | (ur & 0xFFFF0000u);
}
__device__ __forceinline__ u16_t bfhalf(float v, int pl) {
    unsigned u = __float_as_uint(v);
    if (pl == 0) return (u16_t)(u >> 16);
    float rsd = v - __uint_as_float(u & 0xFFFF0000u);
    unsigned ur = __float_as_uint(rsd);
    ur = ur + 0x7FFFu + ((ur >> 16) & 1u);
    return (u16_t)(ur >> 16);
}

// ---------------- prep: derived LTC params + BN folds + weight split/reorder ----------------
__global__ __launch_bounds__(256) void k_prep(
    const float* __restrict__ w2, const float* __restrict__ w3, const float* __restrict__ w4,
    const float* __restrict__ sw, const float* __restrict__ serev, const float* __restrict__ smask,
    const float* __restrict__ w,  const float* __restrict__ erev,  const float* __restrict__ mask,
    const float* __restrict__ gleak, const float* __restrict__ vleak, const float* __restrict__ cm,
    const float* __restrict__ b2, const float* __restrict__ g2, const float* __restrict__ be2,
    const float* __restrict__ m2, const float* __restrict__ v2,
    const float* __restrict__ b4, const float* __restrict__ g4, const float* __restrict__ be4,
    const float* __restrict__ m4, const float* __restrict__ v4,
    float* __restrict__ ws) {
    int gid = blockIdx.x * 256 + threadIdx.x, stride = gridDim.x * 256;
    u16_t* b2f = (u16_t*)(ws + OFF_B2F);
    u16_t* b3f = (u16_t*)(ws + OFF_B3F);
    u16_t* b4f = (u16_t*)(ws + OFF_B4F);
    // conv2 weights (32x32 frag), k = tap*16 + ci
    for (int i = gid; i < 9216; i += stride) {
        int j = i & 7, ln = (i >> 3) & 63;
        int r = i >> 9;
        int s = r % 9, pl = r / 9;
        int k = s * 16 + (ln >> 5) * 8 + j;
        int tap = k >> 4, ci = k & 15;
        int co = ln & 31;
        b2f[i] = bfhalf(w2[(co * 16 + ci) * 9 + tap], pl);
    }
    // conv3 weights (16x16 frag): [pl2][nt4][tap25][ln64][j8]; B[k=ci][n=co]
    for (int i = gid; i < 102400; i += stride) {
        int j = i & 7, ln = (i >> 3) & 63;
        int t = i >> 9;                 // 0..199
        int tap = t % 25, r = t / 25;   // r 0..7
        int nt = r & 3, pl = r >> 2;
        int co = nt * 16 + (ln & 15);
        int ci = (ln >> 4) * 8 + j;
        b3f[i] = bfhalf(w3[(co * 32 + ci) * 25 + tap], pl);
    }
    // conv4 weights (16x16 frag): [pl2][nt8][ks50][ln64][j8]; ks = tap*2 + cihalf
    for (int i = gid; i < 409600; i += stride) {
        int j = i & 7, ln = (i >> 3) & 63;
        int t = i >> 9;                 // 0..799
        int ks = t % 50, r = t / 50;    // r 0..15
        int nt = r & 7, pl = r >> 3;
        int co = nt * 16 + (ln & 15);
        int tap = ks >> 1;
        int ci = (ks & 1) * 32 + (ln >> 4) * 8 + j;
        b4f[i] = bfhalf(w4[(co * 64 + ci) * 25 + tap], pl);
    }
    if (blockIdx.x == 0) {
        float* par = ws + OFF_PAR;
        int tid = threadIdx.x;
        for (int i = tid; i < 304; i += 256) {
            float v_ = softplusf_(sw[i]) * smask[i];
            par[P_SWM + i] = v_;
            par[P_SWME + i] = v_ * serev[i];
        }
        for (int i = tid; i < 361; i += 256) {
            float v_ = softplusf_(w[i]) * mask[i];
            par[P_WP + i] = v_;
            par[P_WPE + i] = v_ * erev[i];
        }
        for (int i = tid; i < 19; i += 256) {
            float g = softplusf_(gleak[i]);
            par[P_GL + i] = g;
            par[P_GLVL + i] = g * vleak[i];
            par[P_CMT + i] = softplusf_(cm[i]) * 6.0f;
        }
        for (int i = tid; i < 32; i += 256) {
            float inv = g2[i] * __frsqrt_rn(v2[i] + 1e-5f);
            par[P_SC2 + i] = inv;
            par[P_SH2 + i] = (b2[i] - m2[i]) * inv + be2[i];
        }
        for (int i = tid; i < 128; i += 256) {
            float inv = g4[i] * __frsqrt_rn(v4[i] + 1e-5f);
            par[P_SC4 + i] = inv;
            par[P_SH4 + i] = (b4[i] - m4[i]) * inv + be4[i];
        }
    }
}

// ---------------- conv1 (VALU) + conv2 (MFMA 32x32), 512 threads ----------------
__global__ __launch_bounds__(512, 4) void k_conv12(
    const float* __restrict__ x, const float* __restrict__ w1, const float* __restrict__ b1,
    const float* __restrict__ ws, unsigned* __restrict__ h2g) {
    __shared__ float xs[784];
    __shared__ unsigned h1s[14300];   // [r29][c29][17] packed (hi,lo)
    const float* par = ws + OFF_PAR;
    int b = blockIdx.x, tid = threadIdx.x;
    {
        for (int i = tid; i < 784; i += 512) xs[i] = x[(long)b * 784 + i];
        uint4* hz = (uint4*)h1s;
        uint4 z; z.x = z.y = z.z = z.w = 0u;
        for (int i = tid; i < 3575; i += 512) hz[i] = z;
    }
    __syncthreads();
    // conv1: 3x3 s1 p0 -> 16x26x26, ReLU, splitpack into h1s
    {
        int co = tid >> 5, slot = tid & 31;
        float wr[9];
        #pragma unroll
        for (int i = 0; i < 9; i++) wr[i] = w1[co * 9 + i];
        float bb = b1[co];
        for (int k = 0; k < 22; k++) {
            int px = slot + (k << 5);
            if (px >= 676) break;
            int oh = px / 26, ow = px % 26;
            float s = bb;
            #pragma unroll
            for (int kh = 0; kh < 3; kh++)
                #pragma unroll
                for (int kw = 0; kw < 3; kw++)
                    s = fmaf(xs[(oh + kh) * 28 + ow + kw], wr[kh * 3 + kw], s);
            h1s[((oh + 2) * 29 + (ow + 2)) * 17 + co] = splitpack(fmaxf(s, 0.f));
        }
    }
    __syncthreads();
    // conv2 GEMM: C[196px x 32co], K=144 (k = tap*16 + ci), 7 m-tiles, 1 per wave
    {
        int wv = tid >> 6, lane = tid & 63;
        int mloc = lane & 31, hf = lane >> 5, half8 = hf * 8;
        const u16_t* B2 = (const u16_t*)(ws + OFF_B2F);
        const short8* pb = (const short8*)B2 + lane;
        float sc = par[P_SC2 + mloc], sh = par[P_SH2 + mloc];
        int mt = wv;
        if (mt < 7) {
            int px = mt * 32 + mloc;
            bool pxok = px < 196;
            int pxc = pxok ? px : 195;
            int oh = pxc / 14, ow = pxc % 14;
            f32x16 acc;
            #pragma unroll
            for (int i = 0; i < 16; i++) acc[i] = 0.f;
            #pragma unroll
            for (int s = 0; s < 9; s++) {
                int kh = s / 3, kw = s % 3;
                int abase = (pxok ? ((oh * 2 + kh) * 29 + (ow * 2 + kw)) * 17 : 0) + half8;
                unsigned w_[8];
                #pragma unroll
                for (int j = 0; j < 8; j++) w_[j] = h1s[abase + j];
                U8 ah, al;
                #pragma unroll
                for (int d = 0; d < 4; d++) {
                    ah.u[d] = PERM_HI(w_[2 * d + 1], w_[2 * d]);
                    al.u[d] = PERM_LO(w_[2 * d + 1], w_[2 * d]);
                }
                short8 bh = pb[s * 64];
                short8 bl = pb[(9 + s) * 64];
                acc = MFMA(ah.v, bh, acc);
                acc = MFMA(ah.v, bl, acc);
                acc = MFMA(al.v, bh, acc);
            }
            #pragma unroll
            for (int r5 = 0; r5 < 16; r5++) {
                int row = (r5 & 3) + 8 * (r5 >> 2) + 4 * hf;
                int pxw = mt * 32 + row;
                if (pxw < 196) {
                    float y = fmaxf(fmaf(acc[r5], sc, sh), 0.f);
                    h2g[(long)b * 6272 + pxw * 32 + mloc] = splitpack(y);
                }
            }
        }
    }
}

// ---- conv3 + conv4 MFMA + sensory + FUSED LTC tail; 2 images/block ----
// conv/sensory identical to R10 (proven). wn/wd stay in LDS; waves 1-3 exit
// after sensory, wave 0 runs the 32x6-step LTC recurrence for both images
// (lanes 0-18 img0, 19-37 img1). The serial tail (~24 us) overlaps the other
// resident block's MFMA phase (MFMA/VALU pipes are independent).
__global__ __launch_bounds__(256, 2) void k_conv34l(
    const unsigned* __restrict__ h2g, const float* __restrict__ b3g,
    const float* __restrict__ inw, const float* __restrict__ inb,
    const float* __restrict__ smu, const float* __restrict__ ssig,
    const float* __restrict__ mu_g, const float* __restrict__ sg_g,
    const float* __restrict__ outw, const float* __restrict__ outb,
    const float* __restrict__ ws,
    float* __restrict__ out, int img0g, int nimg) {
    __shared__ unsigned h2s[12969];  // [img2][px196][33] + zero row @12936; xin/wn/wd overlay
    __shared__ unsigned h3s[6435];   // [img2][px49][65]  + zero row @6370
    const float* par = ws + OFF_PAR;
    int b = blockIdx.x, tid = threadIdx.x;
    int g0 = b * 2;
    int g1 = (g0 + 1 < nimg) ? g0 + 1 : g0;
    {
        const unsigned* s0 = h2g + (long)g0 * 6272;
        const unsigned* s1 = h2g + (long)g1 * 6272;
        for (int i = tid; i < 12544; i += 256) {
            int img = i >= 6272;
            int r = img ? i - 6272 : i;
            h2s[img * 6468 + (r >> 5) * 33 + (r & 31)] = (img ? s1 : s0)[r];
        }
        if (tid < 33) h2s[12936 + tid] = 0u;
        if (tid < 65) h3s[6370 + tid] = 0u;
    }
    __syncthreads();
    int wv = tid >> 6, lane = tid & 63;
    int n16 = lane & 15, quad = lane >> 4, quad8 = quad * 8;

    // ---- conv3: C[img px49 x co64], K=800; wave = (img, mhalf) ----
    {
        int img = wv & 1, mhalf = wv >> 1;
        int imgo = img * 6468;
        int mt0 = mhalf * 2;
        A4 acc[2][4];
        #pragma unroll
        for (int nt = 0; nt < 4; nt++) {
            float bi = b3g[nt * 16 + n16];
            #pragma unroll
            for (int r = 0; r < 4; r++) { acc[0][nt].f[r] = bi; acc[1][nt].f[r] = bi; }
        }
        int oh2[2], ow2[2];
        bool pxok[2];
        #pragma unroll
        for (int mi = 0; mi < 2; mi++) {
            int px = (mt0 + mi) * 16 + n16;
            pxok[mi] = px < 49;
            int pxc = pxok[mi] ? px : 48;
            oh2[mi] = (pxc / 7) * 2 - 2;
            ow2[mi] = (pxc % 7) * 2 - 2;
        }
        const short8* B3 = (const short8*)(const u16_t*)(ws + OFF_B3F);
        const short8* ph0 = B3 + (0 * 25) * 64 + lane;
        const short8* ph1 = B3 + (1 * 25) * 64 + lane;
        const short8* ph2 = B3 + (2 * 25) * 64 + lane;
        const short8* ph3 = B3 + (3 * 25) * 64 + lane;
        const short8* pl0 = B3 + (4 * 25) * 64 + lane;
        const short8* pl1 = B3 + (5 * 25) * 64 + lane;
        const short8* pl2 = B3 + (6 * 25) * 64 + lane;
        const short8* pl3 = B3 + (7 * 25) * 64 + lane;
        #pragma unroll
        for (int kh = 0; kh < 5; kh++) {
            #pragma unroll
            for (int kw = 0; kw < 5; kw++) {
                int s = (kh * 5 + kw) * 64;
                short8 bh0 = ph0[s], bh1 = ph1[s], bh2 = ph2[s], bh3 = ph3[s];
                short8 bl0 = pl0[s], bl1 = pl1[s], bl2 = pl2[s], bl3 = pl3[s];
                #pragma unroll
                for (int mi = 0; mi < 2; mi++) {
                    int ih = oh2[mi] + kh, iw = ow2[mi] + kw;
                    bool ok = pxok[mi] && ((unsigned)ih < 14u) && ((unsigned)iw < 14u);
                    int rowb = ok ? imgo + (ih * 14 + iw) * 33 : 12936;
                    const unsigned* ap = h2s + rowb + quad8;
                    unsigned w_[8];
                    #pragma unroll
                    for (int j = 0; j < 8; j++) w_[j] = ap[j];
                    U8 ah, al;
                    #pragma unroll
                    for (int d = 0; d < 4; d++) {
                        ah.u[d] = PERM_HI(w_[2 * d + 1], w_[2 * d]);
                        al.u[d] = PERM_LO(w_[2 * d + 1], w_[2 * d]);
                    }
                    acc[mi][0].v = MFMA16(ah.v, bh0, acc[mi][0].v);
                    acc[mi][0].v = MFMA16(ah.v, bl0, acc[mi][0].v);
                    acc[mi][0].v = MFMA16(al.v, bh0, acc[mi][0].v);
                    acc[mi][1].v = MFMA16(ah.v, bh1, acc[mi][1].v);
                    acc[mi][1].v = MFMA16(ah.v, bl1, acc[mi][1].v);
                    acc[mi][1].v = MFMA16(al.v, bh1, acc[mi][1].v);
                    acc[mi][2].v = MFMA16(ah.v, bh2, acc[mi][2].v);
                    acc[mi][2].v = MFMA16(ah.v, bl2, acc[mi][2].v);
                    acc[mi][2].v = MFMA16(al.v, bh2, acc[mi][2].v);
                    acc[mi][3].v = MFMA16(ah.v, bh3, acc[mi][3].v);
                    acc[mi][3].v = MFMA16(ah.v, bl3, acc[mi][3].v);
                    acc[mi][3].v = MFMA16(al.v, bh3, acc[mi][3].v);
                }
            }
        }
        // epilogue: ReLU, split, write h3 [img][px][co]; D row = quad*4 + r
        #pragma unroll
        for (int mi = 0; mi < 2; mi++) {
            #pragma unroll
            for (int nt = 0; nt < 4; nt++) {
                int co = nt * 16 + n16;
                #pragma unroll
                for (int r = 0; r < 4; r++) {
                    int pxw = (mt0 + mi) * 16 + quad * 4 + r;
                    if (pxw < 49)
                        h3s[img * 3185 + pxw * 65 + co] = splitpack(fmaxf(acc[mi][nt].f[r], 0.f));
                }
            }
        }
    }
    __syncthreads();
    // ---- conv4: C[px16 x co128] per image, K=1600; wave = 2 n-tiles, loop imgs ----
    {
        int oh = n16 >> 2, ow = n16 & 3;      // m index = pixel = lane&15
        int oh2 = oh * 2 - 2, ow2 = ow * 2 - 2;
        int nt0 = wv * 2, nt1 = nt0 + 1;
        A4 c[2][2];
        #pragma unroll
        for (int mi = 0; mi < 2; mi++)
            #pragma unroll
            for (int r = 0; r < 4; r++) { c[mi][0].f[r] = 0.f; c[mi][1].f[r] = 0.f; }
        const short8* B4 = (const short8*)(const u16_t*)(ws + OFF_B4F);
        const short8* ph0 = B4 + (nt0 * 50) * 64 + lane;
        const short8* ph1 = B4 + (nt1 * 50) * 64 + lane;
        const short8* pl0 = B4 + ((8 + nt0) * 50) * 64 + lane;
        const short8* pl1 = B4 + ((8 + nt1) * 50) * 64 + lane;
        #pragma unroll
        for (int kh = 0; kh < 5; kh++) {
            int ih = oh2 + kh;
            #pragma unroll
            for (int kw = 0; kw < 5; kw++) {
                int iw = ow2 + kw;
                bool ok = ((unsigned)ih < 7u) && ((unsigned)iw < 7u);
                #pragma unroll
                for (int ch = 0; ch < 2; ch++) {
                    int s = ((kh * 5 + kw) * 2 + ch) * 64;
                    short8 bh0 = ph0[s], bl0 = pl0[s];
                    short8 bh1 = ph1[s], bl1 = pl1[s];
                    #pragma unroll
                    for (int mi = 0; mi < 2; mi++) {
                        int rowb = ok ? mi * 3185 + (ih * 7 + iw) * 65 + ch * 32 : 6370;
                        const unsigned* ap = h3s + rowb + quad8;
                        unsigned w_[8];
                        #pragma unroll
                        for (int j = 0; j < 8; j++) w_[j] = ap[j];
                        U8 ah, al;
                        #pragma unroll
                        for (int d = 0; d < 4; d++) {
                            ah.u[d] = PERM_HI(w_[2 * d + 1], w_[2 * d]);
                            al.u[d] = PERM_LO(w_[2 * d + 1], w_[2 * d]);
                        }
                        c[mi][0].v = MFMA16(ah.v, bh0, c[mi][0].v);
                        c[mi][0].v = MFMA16(ah.v, bl0, c[mi][0].v);
                        c[mi][0].v = MFMA16(al.v, bh0, c[mi][0].v);
                        c[mi][1].v = MFMA16(ah.v, bh1, c[mi][1].v);
                        c[mi][1].v = MFMA16(ah.v, bl1, c[mi][1].v);
                        c[mi][1].v = MFMA16(al.v, bh1, c[mi][1].v);
                    }
                }
            }
        }
        // epilogue: BN+ReLU, pool ow-pairs in-reg, oh-pairs via shfl^16, xin
        __syncthreads();   // h2s dead; reuse as xin[img2][32][16] f32 (+ wn/wd after)
        float* xin_s = (float*)h2s;
        #pragma unroll
        for (int mi = 0; mi < 2; mi++) {
            #pragma unroll
            for (int t2 = 0; t2 < 2; t2++) {
                int co = (t2 ? nt1 : nt0) * 16 + n16;
                float sc = par[P_SC4 + co], sh = par[P_SH4 + co];
                float y[4];
                #pragma unroll
                for (int r = 0; r < 4; r++) y[r] = fmaxf(fmaf(c[mi][t2].f[r], sc, sh), 0.f);
                float p0 = fmaxf(y[0], y[1]);
                float p1 = fmaxf(y[2], y[3]);
                p0 = fmaxf(p0, __shfl_xor(p0, 16));
                p1 = fmaxf(p1, __shfl_xor(p1, 16));
                if ((quad & 1) == 0) {
                    int ph_ = quad >> 1;
                    int ts = co >> 2;
                    int f0 = ((co & 3) << 2) + ph_ * 2;
                    xin_s[mi * 512 + ts * 16 + f0] = fmaf(p0, inw[f0], inb[f0]);
                    xin_s[mi * 512 + ts * 16 + f0 + 1] = fmaf(p1, inw[f0 + 1], inb[f0 + 1]);
                }
            }
        }
    }
    __syncthreads();
    // ---- sensory synapses -> LDS wn/wd [img2][32 t][19 n] ----
    {
        const float* xin_s = (const float*)h2s;
        float* wnl = (float*)h2s + 1024;     // 1216 floats
        float* wdl = wnl + 1216;             // 1216 floats (total 3456 < 12969 u32)
        for (int idx = tid; idx < 1216; idx += 256) {
            int img = idx >= 608;
            int r = img ? idx - 608 : idx;
            int tt = r / 19, n = r - tt * 19;
            float nu = 0.f, de = 0.f;
            #pragma unroll
            for (int s = 0; s < 16; s++) {
                float sg = sigmoidf_((xin_s[img * 512 + tt * 16 + s] - smu[s * 19 + n]) * ssig[s * 19 + n]);
                nu = fmaf(par[P_SWME + s * 19 + n], sg, nu);
                de = fmaf(par[P_SWM + s * 19 + n], sg, de);
            }
            wnl[img * 608 + r] = nu;
            wdl[img * 608 + r] = de;
        }
    }
    __syncthreads();
    if (tid >= 64) return;   // waves 1-3 done; wave 0 runs the LTC tail (no more barriers)
    // ---- fused LTC: lanes 0-18 img0, 19-37 img1, 38-63 duplicate img1 (no store) ----
    {
        int li = tid / 19, j = tid - li * 19;
        if (li > 1) { li = 1; j = 18; }
        const float L2E = 1.44269504f;
        float aj[19], bj[19], wpj[19], wpej[19];
        #pragma unroll
        for (int i = 0; i < 19; i++) {
            float mu = mu_g[i * 19 + j];
            float sg = sg_g[i * 19 + j];
            aj[i] = -sg * L2E;
            bj[i] = mu * sg * L2E;
            wpj[i] = par[P_WP + i * 19 + j];
            wpej[i] = par[P_WPE + i * 19 + j];
        }
        float cmt = par[P_CMT + j], gl = par[P_GL + j], glvl = par[P_GLVL + j];
        const float* wnl = (const float*)h2s + 1024;
        const float* wdl = wnl + 1216;
        int base = li * 608 + j;
        float v = 0.f;
        for (int t = 0; t < 32; t++) {
            float wns = wnl[base + t * 19];
            float wds = wdl[base + t * 19];
            #pragma unroll 1
            for (int u = 0; u < 6; u++) {
                float n0 = 0.f, n1 = 0.f, d0 = 0.f, d1 = 0.f;
                #pragma unroll
                for (int i = 0; i < 19; i++) {
                    float vi = __shfl(v, li * 19 + i, 64);
                    float e = __builtin_amdgcn_exp2f(fmaf(vi, aj[i], bj[i]));
                    float s = __builtin_amdgcn_rcpf(1.0f + e);
                    if (i & 1) { n1 = fmaf(wpej[i], s, n1); d1 = fmaf(wpj[i], s, d1); }
                    else       { n0 = fmaf(wpej[i], s, n0); d0 = fmaf(wpj[i], s, d0); }
                }
                float num = fmaf(cmt, v, glvl) + wns + (n0 + n1);
                float den = cmt + gl + wds + (d0 + d1);
                v = num * __builtin_amdgcn_rcpf(den + 1e-8f);
            }
        }
        if (j < 2 && tid < 38) {
            int gi = g0 + li;
            if (gi < nimg)
                out[(long)(img0g + gi) * 2 + j] = fmaf(v, outw[j], outb[j]);
        }
    }
}

extern "C" void kernel_launch(void* const* d_in, const int* in_sizes, int n_in,
                              void* d_out, int out_size, void* d_ws, size_t ws_size,
                              hipStream_t stream) {
    const float* x    = (const float*)d_in[0];
    const float* w1   = (const float*)d_in[1];
    const float* b1   = (const float*)d_in[2];
    const float* w2   = (const float*)d_in[3];
    const float* b2   = (const float*)d_in[4];
    const float* g2   = (const float*)d_in[5];
    const float* be2  = (const float*)d_in[6];
    const float* m2   = (const float*)d_in[7];
    const float* v2   = (const float*)d_in[8];
    const float* w3   = (const float*)d_in[9];
    const float* b3   = (const float*)d_in[10];
    const float* w4   = (const float*)d_in[11];
    const float* b4   = (const float*)d_in[12];
    const float* g4   = (const float*)d_in[13];
    const float* be4  = (const float*)d_in[14];
    const float* m4   = (const float*)d_in[15];
    const float* v4   = (const float*)d_in[16];
    const float* inw  = (const float*)d_in[17];
    const float* inb  = (const float*)d_in[18];
    const float* smu  = (const float*)d_in[19];
    const float* ssig = (const float*)d_in[20];
    const float* sw   = (const float*)d_in[21];
    const float* serv = (const float*)d_in[22];
    const float* smk  = (const float*)d_in[23];
    const float* mu_  = (const float*)d_in[24];
    const float* sig_ = (const float*)d_in[25];
    const float* w_   = (const float*)d_in[26];
    const float* erev = (const float*)d_in[27];
    const float* mask = (const float*)d_in[28];
    const float* glk  = (const float*)d_in[29];
    const float* vlk  = (const float*)d_in[30];
    const float* cm   = (const float*)d_in[31];
    const float* outw = (const float*)d_in[32];
    const float* outb = (const float*)d_in[33];
    float* ws = (float*)d_ws;

    k_prep<<<64, 256, 0, stream>>>(w2, w3, w4, sw, serv, smk, w_, erev, mask,
                                   glk, vlk, cm, b2, g2, be2, m2, v2,
                                   b4, g4, be4, m4, v4, ws);

    // auto-size batch chunk: per-image = h2(6272 u32)
    long avail = (long)(ws_size / 4) - OFF_DYN;
    int chunk = (int)(avail / 6272);
    if (chunk > BATCH) chunk = BATCH;
    if (chunk < 2) chunk = 2;

    unsigned* h2 = (unsigned*)(ws + OFF_DYN);

    for (int c0 = 0; c0 < BATCH; c0 += chunk) {
        int n = (BATCH - c0 < chunk) ? (BATCH - c0) : chunk;
        k_conv12<<<n, 512, 0, stream>>>(x + (long)c0 * 784, w1, b1, ws, h2);
        k_conv34l<<<(n + 1) / 2, 256, 0, stream>>>(h2, b3, inw, inb, smu, ssig,
                                                   mu_, sig_, outw, outb, ws,
                                                   (float*)d_out, c0, n);
    }
}

// Round 12
// 561.751 us; speedup vs baseline: 1.4254x; 1.4254x over previous
//
#include <hip/hip_runtime.h>

#define BATCH 4096
typedef unsigned short u16_t;

// ---- par sub-offsets (floats) ----
#define P_SWM   0
#define P_SWME  304
#define P_WP    608
#define P_WPE   969
#define P_GL    1330
#define P_GLVL  1349
#define P_CMT   1368
#define P_SC2   1392
#define P_SH2   1424
#define P_SC4   1456
#define P_SH4   1584
// par total 1712, reserve 2048

// ---- workspace layout (float offsets) ----
#define OFF_PAR 0L
#define OFF_B2F 2048L      // bf16 frag conv2 W (32x32): [pl2][s9][ln64][j8] = 9216 u16
#define OFF_B3F 6656L      // bf16 frag conv3 W (16x16): [pl2][nt4][tap25][ln64][j8] = 102400 u16
#define OFF_B4F 57856L     // bf16 frag conv4 W (16x16): [pl2][nt8][ks50][ln64][j8] = 409600 u16
#define OFF_DYN 262656L    // then per chunk: wnum[chunk*608], wden[chunk*608], h2[chunk*6272 u32]

typedef __attribute__((ext_vector_type(8))) short short8;
typedef __attribute__((ext_vector_type(16))) float f32x16;
typedef __attribute__((ext_vector_type(4))) float f32x4;
#define MFMA(a, b, c) __builtin_amdgcn_mfma_f32_32x32x16_bf16(a, b, c, 0, 0, 0)
#define MFMA16(a, b, c) __builtin_amdgcn_mfma_f32_16x16x32_bf16(a, b, c, 0, 0, 0)

// byte-select: build (w1.lo16<<16)|w0.lo16 and (w1.hi16<<16)|w0.hi16
#define PERM_HI(w1, w0) __builtin_amdgcn_perm((w1), (w0), 0x05040100u)
#define PERM_LO(w1, w0) __builtin_amdgcn_perm((w1), (w0), 0x07060302u)

union U8 { unsigned u[4]; short8 v; };
union A4 { f32x4 v; float f[4]; };

__device__ __forceinline__ float sigmoidf_(float x) {
    return 1.0f / (1.0f + __expf(-x));
}
__device__ __forceinline__ float softplusf_(float x) { return log1pf(__expf(x)); }

// split fp32 -> packed (hi trunc-bf16 in low16, lo rne-bf16 of residual in high16)
__device__ __forceinline__ unsigned splitpack(float f) {
    unsigned u = __float_as_uint(f);
    float rsd = f - __uint_as_float(u & 0xFFFF0000u);
    unsigned ur = __float_as_uint(rsd);
    ur = ur + 0x7FFFu + ((ur >> 16) & 1u);
    return (u >> 16) | (ur & 0xFFFF0000u);
}
__device__ __forceinline__ u16_t bfhalf(float v, int pl) {
    unsigned u = __float_as_uint(v);
    if (pl == 0) return (u16_t)(u >> 16);
    float rsd = v - __uint_as_float(u & 0xFFFF0000u);
    unsigned ur = __float_as_uint(rsd);
    ur = ur + 0x7FFFu + ((ur >> 16) & 1u);
    return (u16_t)(ur >> 16);
}

// ---------------- prep: derived LTC params + BN folds + weight split/reorder ----------------
__global__ __launch_bounds__(256) void k_prep(
    const float* __restrict__ w2, const float* __restrict__ w3, const float* __restrict__ w4,
    const float* __restrict__ sw, const float* __restrict__ serev, const float* __restrict__ smask,
    const float* __restrict__ w,  const float* __restrict__ erev,  const float* __restrict__ mask,
    const float* __restrict__ gleak, const float* __restrict__ vleak, const float* __restrict__ cm,
    const float* __restrict__ b2, const float* __restrict__ g2, const float* __restrict__ be2,
    const float* __restrict__ m2, const float* __restrict__ v2,
    const float* __restrict__ b4, const float* __restrict__ g4, const float* __restrict__ be4,
    const float* __restrict__ m4, const float* __restrict__ v4,
    float* __restrict__ ws) {
    int gid = blockIdx.x * 256 + threadIdx.x, stride = gridDim.x * 256;
    u16_t* b2f = (u16_t*)(ws + OFF_B2F);
    u16_t* b3f = (u16_t*)(ws + OFF_B3F);
    u16_t* b4f = (u16_t*)(ws + OFF_B4F);
    // conv2 weights (32x32 frag), k = tap*16 + ci
    for (int i = gid; i < 9216; i += stride) {
        int j = i & 7, ln = (i >> 3) & 63;
        int r = i >> 9;
        int s = r % 9, pl = r / 9;
        int k = s * 16 + (ln >> 5) * 8 + j;
        int tap = k >> 4, ci = k & 15;
        int co = ln & 31;
        b2f[i] = bfhalf(w2[(co * 16 + ci) * 9 + tap], pl);
    }
    // conv3 weights (16x16 frag): [pl2][nt4][tap25][ln64][j8]; B[k=ci][n=co]
    for (int i = gid; i < 102400; i += stride) {
        int j = i & 7, ln = (i >> 3) & 63;
        int t = i >> 9;                 // 0..199
        int tap = t % 25, r = t / 25;   // r 0..7
        int nt = r & 3, pl = r >> 2;
        int co = nt * 16 + (ln & 15);
        int ci = (ln >> 4) * 8 + j;
        b3f[i] = bfhalf(w3[(co * 32 + ci) * 25 + tap], pl);
    }
    // conv4 weights (16x16 frag): [pl2][nt8][ks50][ln64][j8]; ks = tap*2 + cihalf
    for (int i = gid; i < 409600; i += stride) {
        int j = i & 7, ln = (i >> 3) & 63;
        int t = i >> 9;                 // 0..799
        int ks = t % 50, r = t / 50;    // r 0..15
        int nt = r & 7, pl = r >> 3;
        int co = nt * 16 + (ln & 15);
        int tap = ks >> 1;
        int ci = (ks & 1) * 32 + (ln >> 4) * 8 + j;
        b4f[i] = bfhalf(w4[(co * 64 + ci) * 25 + tap], pl);
    }
    if (blockIdx.x == 0) {
        float* par = ws + OFF_PAR;
        int tid = threadIdx.x;
        for (int i = tid; i < 304; i += 256) {
            float v_ = softplusf_(sw[i]) * smask[i];
            par[P_SWM + i] = v_;
            par[P_SWME + i] = v_ * serev[i];
        }
        for (int i = tid; i < 361; i += 256) {
            float v_ = softplusf_(w[i]) * mask[i];
            par[P_WP + i] = v_;
            par[P_WPE + i] = v_ * erev[i];
        }
        for (int i = tid; i < 19; i += 256) {
            float g = softplusf_(gleak[i]);
            par[P_GL + i] = g;
            par[P_GLVL + i] = g * vleak[i];
            par[P_CMT + i] = softplusf_(cm[i]) * 6.0f;
        }
        for (int i = tid; i < 32; i += 256) {
            float inv = g2[i] * __frsqrt_rn(v2[i] + 1e-5f);
            par[P_SC2 + i] = inv;
            par[P_SH2 + i] = (b2[i] - m2[i]) * inv + be2[i];
        }
        for (int i = tid; i < 128; i += 256) {
            float inv = g4[i] * __frsqrt_rn(v4[i] + 1e-5f);
            par[P_SC4 + i] = inv;
            par[P_SH4 + i] = (b4[i] - m4[i]) * inv + be4[i];
        }
    }
}

// ---------------- conv1 (VALU) + conv2 (MFMA 32x32), 512 threads ----------------
__global__ __launch_bounds__(512, 4) void k_conv12(
    const float* __restrict__ x, const float* __restrict__ w1, const float* __restrict__ b1,
    const float* __restrict__ ws, unsigned* __restrict__ h2g) {
    __shared__ float xs[784];
    __shared__ unsigned h1s[14300];   // [r29][c29][17] packed (hi,lo)
    const float* par = ws + OFF_PAR;
    int b = blockIdx.x, tid = threadIdx.x;
    {
        for (int i = tid; i < 784; i += 512) xs[i] = x[(long)b * 784 + i];
        uint4* hz = (uint4*)h1s;
        uint4 z; z.x = z.y = z.z = z.w = 0u;
        for (int i = tid; i < 3575; i += 512) hz[i] = z;
    }
    __syncthreads();
    // conv1: 3x3 s1 p0 -> 16x26x26, ReLU, splitpack into h1s
    {
        int co = tid >> 5, slot = tid & 31;
        float wr[9];
        #pragma unroll
        for (int i = 0; i < 9; i++) wr[i] = w1[co * 9 + i];
        float bb = b1[co];
        for (int k = 0; k < 22; k++) {
            int px = slot + (k << 5);
            if (px >= 676) break;
            int oh = px / 26, ow = px % 26;
            float s = bb;
            #pragma unroll
            for (int kh = 0; kh < 3; kh++)
                #pragma unroll
                for (int kw = 0; kw < 3; kw++)
                    s = fmaf(xs[(oh + kh) * 28 + ow + kw], wr[kh * 3 + kw], s);
            h1s[((oh + 2) * 29 + (ow + 2)) * 17 + co] = splitpack(fmaxf(s, 0.f));
        }
    }
    __syncthreads();
    // conv2 GEMM: C[196px x 32co], K=144 (k = tap*16 + ci), 7 m-tiles, 1 per wave
    {
        int wv = tid >> 6, lane = tid & 63;
        int mloc = lane & 31, hf = lane >> 5, half8 = hf * 8;
        const u16_t* B2 = (const u16_t*)(ws + OFF_B2F);
        const short8* pb = (const short8*)B2 + lane;
        float sc = par[P_SC2 + mloc], sh = par[P_SH2 + mloc];
        int mt = wv;
        if (mt < 7) {
            int px = mt * 32 + mloc;
            bool pxok = px < 196;
            int pxc = pxok ? px : 195;
            int oh = pxc / 14, ow = pxc % 14;
            f32x16 acc;
            #pragma unroll
            for (int i = 0; i < 16; i++) acc[i] = 0.f;
            #pragma unroll
            for (int s = 0; s < 9; s++) {
                int kh = s / 3, kw = s % 3;
                int abase = (pxok ? ((oh * 2 + kh) * 29 + (ow * 2 + kw)) * 17 : 0) + half8;
                unsigned w_[8];
                #pragma unroll
                for (int j = 0; j < 8; j++) w_[j] = h1s[abase + j];
                U8 ah, al;
                #pragma unroll
                for (int d = 0; d < 4; d++) {
                    ah.u[d] = PERM_HI(w_[2 * d + 1], w_[2 * d]);
                    al.u[d] = PERM_LO(w_[2 * d + 1], w_[2 * d]);
                }
                short8 bh = pb[s * 64];
                short8 bl = pb[(9 + s) * 64];
                acc = MFMA(ah.v, bh, acc);
                acc = MFMA(ah.v, bl, acc);
                acc = MFMA(al.v, bh, acc);
            }
            #pragma unroll
            for (int r5 = 0; r5 < 16; r5++) {
                int row = (r5 & 3) + 8 * (r5 >> 2) + 4 * hf;
                int pxw = mt * 32 + row;
                if (pxw < 196) {
                    float y = fmaxf(fmaf(acc[r5], sc, sh), 0.f);
                    h2g[(long)b * 6272 + pxw * 32 + mloc] = splitpack(y);
                }
            }
        }
    }
}

// ---- conv3 + conv4 16x16x32 MFMA GEMMs, 2 images/block, B amortized ----
__global__ __launch_bounds__(256, 2) void k_conv34s(
    const unsigned* __restrict__ h2g, const float* __restrict__ b3g,
    const float* __restrict__ inw, const float* __restrict__ inb,
    const float* __restrict__ smu, const float* __restrict__ ssig,
    const float* __restrict__ ws,
    float* __restrict__ wn, float* __restrict__ wd, int nimg) {
    __shared__ unsigned h2s[12969];  // [img2][px196][33] + zero row @12936; xin overlay later
    __shared__ unsigned h3s[6435];   // [img2][px49][65]  + zero row @6370
    const float* par = ws + OFF_PAR;
    int b = blockIdx.x, tid = threadIdx.x;
    int g0 = b * 2;
    int g1 = (g0 + 1 < nimg) ? g0 + 1 : g0;
    {
        const unsigned* s0 = h2g + (long)g0 * 6272;
        const unsigned* s1 = h2g + (long)g1 * 6272;
        for (int i = tid; i < 12544; i += 256) {
            int img = i >= 6272;
            int r = img ? i - 6272 : i;
            h2s[img * 6468 + (r >> 5) * 33 + (r & 31)] = (img ? s1 : s0)[r];
        }
        if (tid < 33) h2s[12936 + tid] = 0u;
        if (tid < 65) h3s[6370 + tid] = 0u;
    }
    __syncthreads();
    int wv = tid >> 6, lane = tid & 63;
    int n16 = lane & 15, quad = lane >> 4, quad8 = quad * 8;

    // ---- conv3: C[img px49 x co64], K=800; wave = (img, mhalf) ----
    {
        int img = wv & 1, mhalf = wv >> 1;
        int imgo = img * 6468;
        int mt0 = mhalf * 2;
        A4 acc[2][4];
        #pragma unroll
        for (int nt = 0; nt < 4; nt++) {
            float bi = b3g[nt * 16 + n16];
            #pragma unroll
            for (int r = 0; r < 4; r++) { acc[0][nt].f[r] = bi; acc[1][nt].f[r] = bi; }
        }
        int oh2[2], ow2[2];
        bool pxok[2];
        #pragma unroll
        for (int mi = 0; mi < 2; mi++) {
            int px = (mt0 + mi) * 16 + n16;
            pxok[mi] = px < 49;
            int pxc = pxok[mi] ? px : 48;
            oh2[mi] = (pxc / 7) * 2 - 2;
            ow2[mi] = (pxc % 7) * 2 - 2;
        }
        const short8* B3 = (const short8*)(const u16_t*)(ws + OFF_B3F);
        const short8* ph0 = B3 + (0 * 25) * 64 + lane;
        const short8* ph1 = B3 + (1 * 25) * 64 + lane;
        const short8* ph2 = B3 + (2 * 25) * 64 + lane;
        const short8* ph3 = B3 + (3 * 25) * 64 + lane;
        const short8* pl0 = B3 + (4 * 25) * 64 + lane;
        const short8* pl1 = B3 + (5 * 25) * 64 + lane;
        const short8* pl2 = B3 + (6 * 25) * 64 + lane;
        const short8* pl3 = B3 + (7 * 25) * 64 + lane;
        #pragma unroll
        for (int kh = 0; kh < 5; kh++) {
            #pragma unroll
            for (int kw = 0; kw < 5; kw++) {
                int s = (kh * 5 + kw) * 64;
                short8 bh0 = ph0[s], bh1 = ph1[s], bh2 = ph2[s], bh3 = ph3[s];
                short8 bl0 = pl0[s], bl1 = pl1[s], bl2 = pl2[s], bl3 = pl3[s];
                #pragma unroll
                for (int mi = 0; mi < 2; mi++) {
                    int ih = oh2[mi] + kh, iw = ow2[mi] + kw;
                    bool ok = pxok[mi] && ((unsigned)ih < 14u) && ((unsigned)iw < 14u);
                    int rowb = ok ? imgo + (ih * 14 + iw) * 33 : 12936;
                    const unsigned* ap = h2s + rowb + quad8;
                    unsigned w_[8];
                    #pragma unroll
                    for (int j = 0; j < 8; j++) w_[j] = ap[j];
                    U8 ah, al;
                    #pragma unroll
                    for (int d = 0; d < 4; d++) {
                        ah.u[d] = PERM_HI(w_[2 * d + 1], w_[2 * d]);
                        al.u[d] = PERM_LO(w_[2 * d + 1], w_[2 * d]);
                    }
                    acc[mi][0].v = MFMA16(ah.v, bh0, acc[mi][0].v);
                    acc[mi][0].v = MFMA16(ah.v, bl0, acc[mi][0].v);
                    acc[mi][0].v = MFMA16(al.v, bh0, acc[mi][0].v);
                    acc[mi][1].v = MFMA16(ah.v, bh1, acc[mi][1].v);
                    acc[mi][1].v = MFMA16(ah.v, bl1, acc[mi][1].v);
                    acc[mi][1].v = MFMA16(al.v, bh1, acc[mi][1].v);
                    acc[mi][2].v = MFMA16(ah.v, bh2, acc[mi][2].v);
                    acc[mi][2].v = MFMA16(ah.v, bl2, acc[mi][2].v);
                    acc[mi][2].v = MFMA16(al.v, bh2, acc[mi][2].v);
                    acc[mi][3].v = MFMA16(ah.v, bh3, acc[mi][3].v);
                    acc[mi][3].v = MFMA16(ah.v, bl3, acc[mi][3].v);
                    acc[mi][3].v = MFMA16(al.v, bh3, acc[mi][3].v);
                }
            }
        }
        // epilogue: ReLU, split, write h3 [img][px][co]; D row = quad*4 + r
        #pragma unroll
        for (int mi = 0; mi < 2; mi++) {
            #pragma unroll
            for (int nt = 0; nt < 4; nt++) {
                int co = nt * 16 + n16;
                #pragma unroll
                for (int r = 0; r < 4; r++) {
                    int pxw = (mt0 + mi) * 16 + quad * 4 + r;
                    if (pxw < 49)
                        h3s[img * 3185 + pxw * 65 + co] = splitpack(fmaxf(acc[mi][nt].f[r], 0.f));
                }
            }
        }
    }
    __syncthreads();
    // ---- conv4: C[px16 x co128] per image, K=1600; wave = 2 n-tiles, loop imgs ----
    {
        int oh = n16 >> 2, ow = n16 & 3;      // m index = pixel = lane&15
        int oh2 = oh * 2 - 2, ow2 = ow * 2 - 2;
        int nt0 = wv * 2, nt1 = nt0 + 1;
        A4 c[2][2];
        #pragma unroll
        for (int mi = 0; mi < 2; mi++)
            #pragma unroll
            for (int r = 0; r < 4; r++) { c[mi][0].f[r] = 0.f; c[mi][1].f[r] = 0.f; }
        const short8* B4 = (const short8*)(const u16_t*)(ws + OFF_B4F);
        const short8* ph0 = B4 + (nt0 * 50) * 64 + lane;
        const short8* ph1 = B4 + (nt1 * 50) * 64 + lane;
        const short8* pl0 = B4 + ((8 + nt0) * 50) * 64 + lane;
        const short8* pl1 = B4 + ((8 + nt1) * 50) * 64 + lane;
        #pragma unroll
        for (int kh = 0; kh < 5; kh++) {
            int ih = oh2 + kh;
            #pragma unroll
            for (int kw = 0; kw < 5; kw++) {
                int iw = ow2 + kw;
                bool ok = ((unsigned)ih < 7u) && ((unsigned)iw < 7u);
                #pragma unroll
                for (int ch = 0; ch < 2; ch++) {
                    int s = ((kh * 5 + kw) * 2 + ch) * 64;
                    short8 bh0 = ph0[s], bl0 = pl0[s];
                    short8 bh1 = ph1[s], bl1 = pl1[s];
                    #pragma unroll
                    for (int mi = 0; mi < 2; mi++) {
                        int rowb = ok ? mi * 3185 + (ih * 7 + iw) * 65 + ch * 32 : 6370;
                        const unsigned* ap = h3s + rowb + quad8;
                        unsigned w_[8];
                        #pragma unroll
                        for (int j = 0; j < 8; j++) w_[j] = ap[j];
                        U8 ah, al;
                        #pragma unroll
                        for (int d = 0; d < 4; d++) {
                            ah.u[d] = PERM_HI(w_[2 * d + 1], w_[2 * d]);
                            al.u[d] = PERM_LO(w_[2 * d + 1], w_[2 * d]);
                        }
                        c[mi][0].v = MFMA16(ah.v, bh0, c[mi][0].v);
                        c[mi][0].v = MFMA16(ah.v, bl0, c[mi][0].v);
                        c[mi][0].v = MFMA16(al.v, bh0, c[mi][0].v);
                        c[mi][1].v = MFMA16(ah.v, bh1, c[mi][1].v);
                        c[mi][1].v = MFMA16(ah.v, bl1, c[mi][1].v);
                        c[mi][1].v = MFMA16(al.v, bh1, c[mi][1].v);
                    }
                }
            }
        }
        // epilogue: BN+ReLU, pool ow-pairs in-reg, oh-pairs via shfl^16, xin
        __syncthreads();   // h2s dead; reuse as xin[img2][32][16] f32
        float* xin_s = (float*)h2s;
        #pragma unroll
        for (int mi = 0; mi < 2; mi++) {
            #pragma unroll
            for (int t2 = 0; t2 < 2; t2++) {
                int co = (t2 ? nt1 : nt0) * 16 + n16;
                float sc = par[P_SC4 + co], sh = par[P_SH4 + co];
                float y[4];
                #pragma unroll
                for (int r = 0; r < 4; r++) y[r] = fmaxf(fmaf(c[mi][t2].f[r], sc, sh), 0.f);
                float p0 = fmaxf(y[0], y[1]);
                float p1 = fmaxf(y[2], y[3]);
                p0 = fmaxf(p0, __shfl_xor(p0, 16));
                p1 = fmaxf(p1, __shfl_xor(p1, 16));
                if ((quad & 1) == 0) {
                    int ph_ = quad >> 1;
                    int ts = co >> 2;
                    int f0 = ((co & 3) << 2) + ph_ * 2;
                    xin_s[mi * 512 + ts * 16 + f0] = fmaf(p0, inw[f0], inb[f0]);
                    xin_s[mi * 512 + ts * 16 + f0 + 1] = fmaf(p1, inw[f0 + 1], inb[f0 + 1]);
                }
            }
        }
    }
    __syncthreads();
    // ---- sensory synapses per image: wnum/wden [32 t][19 n] ----
    const float* xin_s = (const float*)h2s;
    for (int idx = tid; idx < 1216; idx += 256) {
        int img = idx >= 608;
        int r = img ? idx - 608 : idx;
        int gi = g0 + img;
        if (gi >= nimg) break;
        int tt = r / 19, n = r - tt * 19;
        float nu = 0.f, de = 0.f;
        #pragma unroll
        for (int s = 0; s < 16; s++) {
            float sg = sigmoidf_((xin_s[img * 512 + tt * 16 + s] - smu[s * 19 + n]) * ssig[s * 19 + n]);
            nu = fmaf(par[P_SWME + s * 19 + n], sg, nu);
            de = fmaf(par[P_SWM + s * 19 + n], sg, de);
        }
        wn[((long)gi * 32 + tt) * 19 + n] = nu;
        wd[((long)gi * 32 + tt) * 19 + n] = de;
    }
}

// ---------------- LTC recurrence: 3 images x 19 neurons per wave ----------------
// All 19 shuffles batched into a register array BEFORE the compute loop: the
// compiler then issues 19 independent ds_bpermute + ONE lgkmcnt wait, instead
// of 19 serialized shuffle->use round-trips (~95 cyc each, the R10 bottleneck).
__global__ __launch_bounds__(256, 2) void k_ltc(
    const float* __restrict__ mu_g, const float* __restrict__ sg_g,
    const float* __restrict__ ws,
    const float* __restrict__ wn, const float* __restrict__ wd,
    const float* __restrict__ outw, const float* __restrict__ outb,
    float* __restrict__ out, int img0, int nimg) {
    const float* par = ws + OFF_PAR;
    int tid = threadIdx.x, wave = tid >> 6, lane = tid & 63;
    int li = lane / 19, j = lane - li * 19;
    if (li > 2) { li = 2; j = 18; }
    int il = blockIdx.x * 12 + wave * 3 + li;
    int ilc = il < nimg ? il : nimg - 1;

    const float L2E = 1.44269504f;
    float aj[19], bj[19], wpj[19], wpej[19];
    #pragma unroll
    for (int i = 0; i < 19; i++) {
        float mu = mu_g[i * 19 + j];
        float sg = sg_g[i * 19 + j];
        aj[i] = -sg * L2E;
        bj[i] = mu * sg * L2E;
        wpj[i] = par[P_WP + i * 19 + j];
        wpej[i] = par[P_WPE + i * 19 + j];
    }
    float cmt = par[P_CMT + j], gl = par[P_GL + j], glvl = par[P_GLVL + j];
    float v = 0.f;
    long base0 = (long)ilc * 608 + j;
    float wns = wn[base0], wds = wd[base0];
    int lbase = li * 19;
    for (int t = 0; t < 32; t++) {
        float wns_n = 0.f, wds_n = 0.f;
        if (t < 31) {
            long basen = base0 + (t + 1) * 19;
            wns_n = wn[basen];
            wds_n = wd[basen];
        }
        #pragma unroll 1
        for (int u = 0; u < 6; u++) {
            // batch all broadcasts first -> single waitcnt
            float vi[19];
            #pragma unroll
            for (int i = 0; i < 19; i++) vi[i] = __shfl(v, lbase + i, 64);
            // batch the 19 transcendentals
            float sg[19];
            #pragma unroll
            for (int i = 0; i < 19; i++)
                sg[i] = __builtin_amdgcn_exp2f(fmaf(vi[i], aj[i], bj[i]));
            float n0 = 0.f, n1 = 0.f, d0 = 0.f, d1 = 0.f;
            #pragma unroll
            for (int i = 0; i < 19; i++) {
                float s = __builtin_amdgcn_rcpf(1.0f + sg[i]);
                if (i & 1) { n1 = fmaf(wpej[i], s, n1); d1 = fmaf(wpj[i], s, d1); }
                else       { n0 = fmaf(wpej[i], s, n0); d0 = fmaf(wpj[i], s, d0); }
            }
            float num = fmaf(cmt, v, glvl) + wns + (n0 + n1);
            float den = cmt + gl + wds + (d0 + d1);
            v = num * __builtin_amdgcn_rcpf(den + 1e-8f);
        }
        wns = wns_n; wds = wds_n;
    }
    if (j < 2 && il < nimg && lane < 57)
        out[(long)(img0 + il) * 2 + j] = fmaf(v, outw[j], outb[j]);
}

extern "C" void kernel_launch(void* const* d_in, const int* in_sizes, int n_in,
                              void* d_out, int out_size, void* d_ws, size_t ws_size,
                              hipStream_t stream) {
    const float* x    = (const float*)d_in[0];
    const float* w1   = (const float*)d_in[1];
    const float* b1   = (const float*)d_in[2];
    const float* w2   = (const float*)d_in[3];
    const float* b2   = (const float*)d_in[4];
    const float* g2   = (const float*)d_in[5];
    const float* be2  = (const float*)d_in[6];
    const float* m2   = (const float*)d_in[7];
    const float* v2   = (const float*)d_in[8];
    const float* w3   = (const float*)d_in[9];
    const float* b3   = (const float*)d_in[10];
    const float* w4   = (const float*)d_in[11];
    const float* b4   = (const float*)d_in[12];
    const float* g4   = (const float*)d_in[13];
    const float* be4  = (const float*)d_in[14];
    const float* m4   = (const float*)d_in[15];
    const float* v4   = (const float*)d_in[16];
    const float* inw  = (const float*)d_in[17];
    const float* inb  = (const float*)d_in[18];
    const float* smu  = (const float*)d_in[19];
    const float* ssig = (const float*)d_in[20];
    const float* sw   = (const float*)d_in[21];
    const float* serv = (const float*)d_in[22];
    const float* smk  = (const float*)d_in[23];
    const float* mu_  = (const float*)d_in[24];
    const float* sig_ = (const float*)d_in[25];
    const float* w_   = (const float*)d_in[26];
    const float* erev = (const float*)d_in[27];
    const float* mask = (const float*)d_in[28];
    const float* glk  = (const float*)d_in[29];
    const float* vlk  = (const float*)d_in[30];
    const float* cm   = (const float*)d_in[31];
    const float* outw = (const float*)d_in[32];
    const float* outb = (const float*)d_in[33];
    float* ws = (float*)d_ws;

    k_prep<<<64, 256, 0, stream>>>(w2, w3, w4, sw, serv, smk, w_, erev, mask,
                                   glk, vlk, cm, b2, g2, be2, m2, v2,
                                   b4, g4, be4, m4, v4, ws);

    // auto-size batch chunk: per-image = h2(6272 u32) + wn/wd(1216 f32)
    long avail = (long)(ws_size / 4) - OFF_DYN;
    long per = 6272 + 1216;
    int chunk = (int)(avail / per);
    if (chunk > BATCH) chunk = BATCH;
    if (chunk < 2) chunk = 2;

    float* wnp = ws + OFF_DYN;
    float* wdp = wnp + (long)chunk * 608;
    unsigned* h2 = (unsigned*)(wdp + (long)chunk * 608);

    for (int c0 = 0; c0 < BATCH; c0 += chunk) {
        int n = (BATCH - c0 < chunk) ? (BATCH - c0) : chunk;
        k_conv12<<<n, 512, 0, stream>>>(x + (long)c0 * 784, w1, b1, ws, h2);
        k_conv34s<<<(n + 1) / 2, 256, 0, stream>>>(h2, b3, inw, inb, smu, ssig, ws,
                                                   wnp, wdp, n);
        k_ltc<<<(n + 11) / 12, 256, 0, stream>>>(mu_, sig_, ws, wnp, wdp, outw, outb,
                                                 (float*)d_out, c0, n);
    }
}

// Round 14
// 561.270 us; speedup vs baseline: 1.4266x; 1.0009x over previous
//
#include <hip/hip_runtime.h>

#define BATCH 4096
typedef unsigned short u16_t;

// ---- par sub-offsets (floats) ----
#define P_SWM   0
#define P_SWME  304
#define P_WP    608
#define P_WPE   969
#define P_GL    1330
#define P_GLVL  1349
#define P_CMT   1368
#define P_SC2   1392
#define P_SH2   1424
#define P_SC4   1456
#define P_SH4   1584
// par total 1712, reserve 2048

// ---- workspace layout (float offsets) ----
#define OFF_PAR 0L
#define OFF_B2F 2048L      // bf16 frag conv2 W (32x32): [pl2][s9][ln64][j8] = 9216 u16
#define OFF_B3F 6656L      // bf16 frag conv3 W (16x16): [pl2][nt4][tap25][ln64][j8] = 102400 u16
#define OFF_B4F 57856L     // bf16 frag conv4 W (16x16): [pl2][nt8][ks50][ln64][j8] = 409600 u16
#define OFF_DYN 262656L    // then per chunk: wnum[chunk*608], wden[chunk*608], h2[chunk*6272 u32]

typedef __attribute__((ext_vector_type(8))) short short8;
typedef __attribute__((ext_vector_type(16))) float f32x16;
typedef __attribute__((ext_vector_type(4))) float f32x4;
#define MFMA(a, b, c) __builtin_amdgcn_mfma_f32_32x32x16_bf16(a, b, c, 0, 0, 0)
#define MFMA16(a, b, c) __builtin_amdgcn_mfma_f32_16x16x32_bf16(a, b, c, 0, 0, 0)

// byte-select: build (w1.lo16<<16)|w0.lo16 and (w1.hi16<<16)|w0.hi16
#define PERM_HI(w1, w0) __builtin_amdgcn_perm((w1), (w0), 0x05040100u)
#define PERM_LO(w1, w0) __builtin_amdgcn_perm((w1), (w0), 0x07060302u)

union U8 { unsigned u[4]; short8 v; };
union A4 { f32x4 v; float f[4]; };

__device__ __forceinline__ float sigmoidf_(float x) {
    return 1.0f / (1.0f + __expf(-x));
}
__device__ __forceinline__ float softplusf_(float x) { return log1pf(__expf(x)); }

// split fp32 -> packed (hi trunc-bf16 in low16, lo rne-bf16 of residual in high16)
__device__ __forceinline__ unsigned splitpack(float f) {
    unsigned u = __float_as_uint(f);
    float rsd = f - __uint_as_float(u & 0xFFFF0000u);
    unsigned ur = __float_as_uint(rsd);
    ur = ur + 0x7FFFu + ((ur >> 16) & 1u);
    return (u >> 16) | (ur & 0xFFFF0000u);
}
__device__ __forceinline__ u16_t bfhalf(float v, int pl) {
    unsigned u = __float_as_uint(v);
    if (pl == 0) return (u16_t)(u >> 16);
    float rsd = v - __uint_as_float(u & 0xFFFF0000u);
    unsigned ur = __float_as_uint(rsd);
    ur = ur + 0x7FFFu + ((ur >> 16) & 1u);
    return (u16_t)(ur >> 16);
}

// ---------------- prep: derived LTC params + BN folds + weight split/reorder ----------------
__global__ __launch_bounds__(256) void k_prep(
    const float* __restrict__ w2, const float* __restrict__ w3, const float* __restrict__ w4,
    const float* __restrict__ sw, const float* __restrict__ serev, const float* __restrict__ smask,
    const float* __restrict__ w,  const float* __restrict__ erev,  const float* __restrict__ mask,
    const float* __restrict__ gleak, const float* __restrict__ vleak, const float* __restrict__ cm,
    const float* __restrict__ b2, const float* __restrict__ g2, const float* __restrict__ be2,
    const float* __restrict__ m2, const float* __restrict__ v2,
    const float* __restrict__ b4, const float* __restrict__ g4, const float* __restrict__ be4,
    const float* __restrict__ m4, const float* __restrict__ v4,
    float* __restrict__ ws) {
    int gid = blockIdx.x * 256 + threadIdx.x, stride = gridDim.x * 256;
    u16_t* b2f = (u16_t*)(ws + OFF_B2F);
    u16_t* b3f = (u16_t*)(ws + OFF_B3F);
    u16_t* b4f = (u16_t*)(ws + OFF_B4F);
    // conv2 weights (32x32 frag), k = tap*16 + ci
    for (int i = gid; i < 9216; i += stride) {
        int j = i & 7, ln = (i >> 3) & 63;
        int r = i >> 9;
        int s = r % 9, pl = r / 9;
        int k = s * 16 + (ln >> 5) * 8 + j;
        int tap = k >> 4, ci = k & 15;
        int co = ln & 31;
        b2f[i] = bfhalf(w2[(co * 16 + ci) * 9 + tap], pl);
    }
    // conv3 weights (16x16 frag): [pl2][nt4][tap25][ln64][j8]; B[k=ci][n=co]
    for (int i = gid; i < 102400; i += stride) {
        int j = i & 7, ln = (i >> 3) & 63;
        int t = i >> 9;                 // 0..199
        int tap = t % 25, r = t / 25;   // r 0..7
        int nt = r & 3, pl = r >> 2;
        int co = nt * 16 + (ln & 15);
        int ci = (ln >> 4) * 8 + j;
        b3f[i] = bfhalf(w3[(co * 32 + ci) * 25 + tap], pl);
    }
    // conv4 weights (16x16 frag): [pl2][nt8][ks50][ln64][j8]; ks = tap*2 + cihalf
    for (int i = gid; i < 409600; i += stride) {
        int j = i & 7, ln = (i >> 3) & 63;
        int t = i >> 9;                 // 0..799
        int ks = t % 50, r = t / 50;    // r 0..15
        int nt = r & 7, pl = r >> 3;
        int co = nt * 16 + (ln & 15);
        int tap = ks >> 1;
        int ci = (ks & 1) * 32 + (ln >> 4) * 8 + j;
        b4f[i] = bfhalf(w4[(co * 64 + ci) * 25 + tap], pl);
    }
    if (blockIdx.x == 0) {
        float* par = ws + OFF_PAR;
        int tid = threadIdx.x;
        for (int i = tid; i < 304; i += 256) {
            float v_ = softplusf_(sw[i]) * smask[i];
            par[P_SWM + i] = v_;
            par[P_SWME + i] = v_ * serev[i];
        }
        for (int i = tid; i < 361; i += 256) {
            float v_ = softplusf_(w[i]) * mask[i];
            par[P_WP + i] = v_;
            par[P_WPE + i] = v_ * erev[i];
        }
        for (int i = tid; i < 19; i += 256) {
            float g = softplusf_(gleak[i]);
            par[P_GL + i] = g;
            par[P_GLVL + i] = g * vleak[i];
            par[P_CMT + i] = softplusf_(cm[i]) * 6.0f;
        }
        for (int i = tid; i < 32; i += 256) {
            float inv = g2[i] * __frsqrt_rn(v2[i] + 1e-5f);
            par[P_SC2 + i] = inv;
            par[P_SH2 + i] = (b2[i] - m2[i]) * inv + be2[i];
        }
        for (int i = tid; i < 128; i += 256) {
            float inv = g4[i] * __frsqrt_rn(v4[i] + 1e-5f);
            par[P_SC4 + i] = inv;
            par[P_SH4 + i] = (b4[i] - m4[i]) * inv + be4[i];
        }
    }
}

// ---------------- conv1 (VALU) + conv2 (MFMA 32x32), 512 threads ----------------
// (R12-proven version: padded 29x29x17 h1, full zero-fill.)
__global__ __launch_bounds__(512, 4) void k_conv12(
    const float* __restrict__ x, const float* __restrict__ w1, const float* __restrict__ b1,
    const float* __restrict__ ws, unsigned* __restrict__ h2g) {
    __shared__ float xs[784];
    __shared__ unsigned h1s[14300];   // [r29][c29][17] packed (hi,lo)
    const float* par = ws + OFF_PAR;
    int b = blockIdx.x, tid = threadIdx.x;
    {
        for (int i = tid; i < 784; i += 512) xs[i] = x[(long)b * 784 + i];
        uint4* hz = (uint4*)h1s;
        uint4 z; z.x = z.y = z.z = z.w = 0u;
        for (int i = tid; i < 3575; i += 512) hz[i] = z;
    }
    __syncthreads();
    // conv1: 3x3 s1 p0 -> 16x26x26, ReLU, splitpack into h1s
    {
        int co = tid >> 5, slot = tid & 31;
        float wr[9];
        #pragma unroll
        for (int i = 0; i < 9; i++) wr[i] = w1[co * 9 + i];
        float bb = b1[co];
        for (int k = 0; k < 22; k++) {
            int px = slot + (k << 5);
            if (px >= 676) break;
            int oh = px / 26, ow = px % 26;
            float s = bb;
            #pragma unroll
            for (int kh = 0; kh < 3; kh++)
                #pragma unroll
                for (int kw = 0; kw < 3; kw++)
                    s = fmaf(xs[(oh + kh) * 28 + ow + kw], wr[kh * 3 + kw], s);
            h1s[((oh + 2) * 29 + (ow + 2)) * 17 + co] = splitpack(fmaxf(s, 0.f));
        }
    }
    __syncthreads();
    // conv2 GEMM: C[196px x 32co], K=144 (k = tap*16 + ci), 7 m-tiles, 1 per wave
    {
        int wv = tid >> 6, lane = tid & 63;
        int mloc = lane & 31, hf = lane >> 5, half8 = hf * 8;
        const u16_t* B2 = (const u16_t*)(ws + OFF_B2F);
        const short8* pb = (const short8*)B2 + lane;
        float sc = par[P_SC2 + mloc], sh = par[P_SH2 + mloc];
        int mt = wv;
        if (mt < 7) {
            int px = mt * 32 + mloc;
            bool pxok = px < 196;
            int pxc = pxok ? px : 195;
            int oh = pxc / 14, ow = pxc % 14;
            f32x16 acc;
            #pragma unroll
            for (int i = 0; i < 16; i++) acc[i] = 0.f;
            #pragma unroll
            for (int s = 0; s < 9; s++) {
                int kh = s / 3, kw = s % 3;
                int abase = (pxok ? ((oh * 2 + kh) * 29 + (ow * 2 + kw)) * 17 : 0) + half8;
                unsigned w_[8];
                #pragma unroll
                for (int j = 0; j < 8; j++) w_[j] = h1s[abase + j];
                U8 ah, al;
                #pragma unroll
                for (int d = 0; d < 4; d++) {
                    ah.u[d] = PERM_HI(w_[2 * d + 1], w_[2 * d]);
                    al.u[d] = PERM_LO(w_[2 * d + 1], w_[2 * d]);
                }
                short8 bh = pb[s * 64];
                short8 bl = pb[(9 + s) * 64];
                acc = MFMA(ah.v, bh, acc);
                acc = MFMA(ah.v, bl, acc);
                acc = MFMA(al.v, bh, acc);
            }
            #pragma unroll
            for (int r5 = 0; r5 < 16; r5++) {
                int row = (r5 & 3) + 8 * (r5 >> 2) + 4 * hf;
                int pxw = mt * 32 + row;
                if (pxw < 196) {
                    float y = fmaxf(fmaf(acc[r5], sc, sh), 0.f);
                    h2g[(long)b * 6272 + pxw * 32 + mloc] = splitpack(y);
                }
            }
        }
    }
}

// ---- conv3 + conv4 16x16x32 MFMA GEMMs, 2 images/block, B amortized ----
// Strides retuned: h2s stride 34 (8B-aligned, bank=(2px+k)%32 conflict-free),
// h3s stride 68 (16B-aligned -> ds_read_b128, bank=(4R+k)%32 2-way=free).
// LDS = (13362 + 6732)*4 = 80376 B -> 2 blocks/CU.
__global__ __launch_bounds__(256, 2) void k_conv34s(
    const unsigned* __restrict__ h2g, const float* __restrict__ b3g,
    const float* __restrict__ inw, const float* __restrict__ inb,
    const float* __restrict__ smu, const float* __restrict__ ssig,
    const float* __restrict__ ws,
    float* __restrict__ wn, float* __restrict__ wd, int nimg) {
    __shared__ unsigned h2s[13362];  // [img2][px196][34] + zero row @13328; xin overlay later
    __shared__ unsigned h3s[6732];   // [img2][px49][68]  + zero row @6664
    const float* par = ws + OFF_PAR;
    int b = blockIdx.x, tid = threadIdx.x;
    int g0 = b * 2;
    int g1 = (g0 + 1 < nimg) ? g0 + 1 : g0;
    {
        const unsigned* s0 = h2g + (long)g0 * 6272;
        const unsigned* s1 = h2g + (long)g1 * 6272;
        for (int i = tid; i < 12544; i += 256) {
            int img = i >= 6272;
            int r = img ? i - 6272 : i;
            h2s[img * 6664 + (r >> 5) * 34 + (r & 31)] = (img ? s1 : s0)[r];
        }
        if (tid < 34) h2s[13328 + tid] = 0u;
        if (tid < 68) h3s[6664 + tid] = 0u;
    }
    __syncthreads();
    int wv = tid >> 6, lane = tid & 63;
    int n16 = lane & 15, quad = lane >> 4, quad8 = quad * 8;

    // ---- conv3: C[img px49 x co64], K=800; wave = (img, mhalf) ----
    {
        int img = wv & 1, mhalf = wv >> 1;
        int imgo = img * 6664;
        int mt0 = mhalf * 2;
        A4 acc[2][4];
        #pragma unroll
        for (int nt = 0; nt < 4; nt++) {
            float bi = b3g[nt * 16 + n16];
            #pragma unroll
            for (int r = 0; r < 4; r++) { acc[0][nt].f[r] = bi; acc[1][nt].f[r] = bi; }
        }
        int oh2[2], ow2[2];
        bool pxok[2];
        #pragma unroll
        for (int mi = 0; mi < 2; mi++) {
            int px = (mt0 + mi) * 16 + n16;
            pxok[mi] = px < 49;
            int pxc = pxok[mi] ? px : 48;
            oh2[mi] = (pxc / 7) * 2 - 2;
            ow2[mi] = (pxc % 7) * 2 - 2;
        }
        const short8* B3 = (const short8*)(const u16_t*)(ws + OFF_B3F);
        const short8* ph0 = B3 + (0 * 25) * 64 + lane;
        const short8* ph1 = B3 + (1 * 25) * 64 + lane;
        const short8* ph2 = B3 + (2 * 25) * 64 + lane;
        const short8* ph3 = B3 + (3 * 25) * 64 + lane;
        const short8* pl0 = B3 + (4 * 25) * 64 + lane;
        const short8* pl1 = B3 + (5 * 25) * 64 + lane;
        const short8* pl2 = B3 + (6 * 25) * 64 + lane;
        const short8* pl3 = B3 + (7 * 25) * 64 + lane;
        #pragma unroll
        for (int kh = 0; kh < 5; kh++) {
            #pragma unroll
            for (int kw = 0; kw < 5; kw++) {
                int s = (kh * 5 + kw) * 64;
                short8 bh0 = ph0[s], bh1 = ph1[s], bh2 = ph2[s], bh3 = ph3[s];
                short8 bl0 = pl0[s], bl1 = pl1[s], bl2 = pl2[s], bl3 = pl3[s];
                #pragma unroll
                for (int mi = 0; mi < 2; mi++) {
                    int ih = oh2[mi] + kh, iw = ow2[mi] + kw;
                    bool ok = pxok[mi] && ((unsigned)ih < 14u) && ((unsigned)iw < 14u);
                    int rowb = ok ? imgo + (ih * 14 + iw) * 34 : 13328;
                    const unsigned* ap = h2s + rowb + quad8;
                    unsigned w_[8];
                    #pragma unroll
                    for (int j = 0; j < 8; j++) w_[j] = ap[j];
                    U8 ah, al;
                    #pragma unroll
                    for (int d = 0; d < 4; d++) {
                        ah.u[d] = PERM_HI(w_[2 * d + 1], w_[2 * d]);
                        al.u[d] = PERM_LO(w_[2 * d + 1], w_[2 * d]);
                    }
                    acc[mi][0].v = MFMA16(ah.v, bh0, acc[mi][0].v);
                    acc[mi][0].v = MFMA16(ah.v, bl0, acc[mi][0].v);
                    acc[mi][0].v = MFMA16(al.v, bh0, acc[mi][0].v);
                    acc[mi][1].v = MFMA16(ah.v, bh1, acc[mi][1].v);
                    acc[mi][1].v = MFMA16(ah.v, bl1, acc[mi][1].v);
                    acc[mi][1].v = MFMA16(al.v, bh1, acc[mi][1].v);
                    acc[mi][2].v = MFMA16(ah.v, bh2, acc[mi][2].v);
                    acc[mi][2].v = MFMA16(ah.v, bl2, acc[mi][2].v);
                    acc[mi][2].v = MFMA16(al.v, bh2, acc[mi][2].v);
                    acc[mi][3].v = MFMA16(ah.v, bh3, acc[mi][3].v);
                    acc[mi][3].v = MFMA16(ah.v, bl3, acc[mi][3].v);
                    acc[mi][3].v = MFMA16(al.v, bh3, acc[mi][3].v);
                }
            }
        }
        // epilogue: ReLU, split, write h3 [img][px][co]; D row = quad*4 + r
        #pragma unroll
        for (int mi = 0; mi < 2; mi++) {
            #pragma unroll
            for (int nt = 0; nt < 4; nt++) {
                int co = nt * 16 + n16;
                #pragma unroll
                for (int r = 0; r < 4; r++) {
                    int pxw = (mt0 + mi) * 16 + quad * 4 + r;
                    if (pxw < 49)
                        h3s[img * 3332 + pxw * 68 + co] = splitpack(fmaxf(acc[mi][nt].f[r], 0.f));
                }
            }
        }
    }
    __syncthreads();
    // ---- conv4: C[px16 x co128] per image, K=1600; wave = 2 n-tiles, loop imgs ----
    {
        int oh = n16 >> 2, ow = n16 & 3;      // m index = pixel = lane&15
        int oh2 = oh * 2 - 2, ow2 = ow * 2 - 2;
        int nt0 = wv * 2, nt1 = nt0 + 1;
        A4 c[2][2];
        #pragma unroll
        for (int mi = 0; mi < 2; mi++)
            #pragma unroll
            for (int r = 0; r < 4; r++) { c[mi][0].f[r] = 0.f; c[mi][1].f[r] = 0.f; }
        const short8* B4 = (const short8*)(const u16_t*)(ws + OFF_B4F);
        const short8* ph0 = B4 + (nt0 * 50) * 64 + lane;
        const short8* ph1 = B4 + (nt1 * 50) * 64 + lane;
        const short8* pl0 = B4 + ((8 + nt0) * 50) * 64 + lane;
        const short8* pl1 = B4 + ((8 + nt1) * 50) * 64 + lane;
        #pragma unroll
        for (int kh = 0; kh < 5; kh++) {
            int ih = oh2 + kh;
            #pragma unroll
            for (int kw = 0; kw < 5; kw++) {
                int iw = ow2 + kw;
                bool ok = ((unsigned)ih < 7u) && ((unsigned)iw < 7u);
                #pragma unroll
                for (int ch = 0; ch < 2; ch++) {
                    int s = ((kh * 5 + kw) * 2 + ch) * 64;
                    short8 bh0 = ph0[s], bl0 = pl0[s];
                    short8 bh1 = ph1[s], bl1 = pl1[s];
                    #pragma unroll
                    for (int mi = 0; mi < 2; mi++) {
                        int rowb = ok ? mi * 3332 + (ih * 7 + iw) * 68 + ch * 32 : 6664;
                        const unsigned* ap = h3s + rowb + quad8;
                        unsigned w_[8];
                        #pragma unroll
                        for (int j = 0; j < 8; j++) w_[j] = ap[j];
                        U8 ah, al;
                        #pragma unroll
                        for (int d = 0; d < 4; d++) {
                            ah.u[d] = PERM_HI(w_[2 * d + 1], w_[2 * d]);
                            al.u[d] = PERM_LO(w_[2 * d + 1], w_[2 * d]);
                        }
                        c[mi][0].v = MFMA16(ah.v, bh0, c[mi][0].v);
                        c[mi][0].v = MFMA16(ah.v, bl0, c[mi][0].v);
                        c[mi][0].v = MFMA16(al.v, bh0, c[mi][0].v);
                        c[mi][1].v = MFMA16(ah.v, bh1, c[mi][1].v);
                        c[mi][1].v = MFMA16(ah.v, bl1, c[mi][1].v);
                        c[mi][1].v = MFMA16(al.v, bh1, c[mi][1].v);
                    }
                }
            }
        }
        // epilogue: BN+ReLU, pool ow-pairs in-reg, oh-pairs via shfl^16, xin
        __syncthreads();   // h2s dead; reuse as xin[img2][32][16] f32
        float* xin_s = (float*)h2s;
        #pragma unroll
        for (int mi = 0; mi < 2; mi++) {
            #pragma unroll
            for (int t2 = 0; t2 < 2; t2++) {
                int co = (t2 ? nt1 : nt0) * 16 + n16;
                float sc = par[P_SC4 + co], sh = par[P_SH4 + co];
                float y[4];
                #pragma unroll
                for (int r = 0; r < 4; r++) y[r] = fmaxf(fmaf(c[mi][t2].f[r], sc, sh), 0.f);
                float p0 = fmaxf(y[0], y[1]);
                float p1 = fmaxf(y[2], y[3]);
                p0 = fmaxf(p0, __shfl_xor(p0, 16));
                p1 = fmaxf(p1, __shfl_xor(p1, 16));
                if ((quad & 1) == 0) {
                    int ph_ = quad >> 1;
                    int ts = co >> 2;
                    int f0 = ((co & 3) << 2) + ph_ * 2;
                    xin_s[mi * 512 + ts * 16 + f0] = fmaf(p0, inw[f0], inb[f0]);
                    xin_s[mi * 512 + ts * 16 + f0 + 1] = fmaf(p1, inw[f0 + 1], inb[f0 + 1]);
                }
            }
        }
    }
    __syncthreads();
    // ---- sensory synapses per image: wnum/wden [32 t][19 n] ----
    const float* xin_s = (const float*)h2s;
    for (int idx = tid; idx < 1216; idx += 256) {
        int img = idx >= 608;
        int r = img ? idx - 608 : idx;
        int gi = g0 + img;
        if (gi >= nimg) break;
        int tt = r / 19, n = r - tt * 19;
        float nu = 0.f, de = 0.f;
        #pragma unroll
        for (int s = 0; s < 16; s++) {
            float sg = sigmoidf_((xin_s[img * 512 + tt * 16 + s] - smu[s * 19 + n]) * ssig[s * 19 + n]);
            nu = fmaf(par[P_SWME + s * 19 + n], sg, nu);
            de = fmaf(par[P_SWM + s * 19 + n], sg, de);
        }
        wn[((long)gi * 32 + tt) * 19 + n] = nu;
        wd[((long)gi * 32 + tt) * 19 + n] = de;
    }
}

// ---------------- LTC recurrence: 3 images x 19 neurons per wave ----------------
__global__ __launch_bounds__(256, 2) void k_ltc(
    const float* __restrict__ mu_g, const float* __restrict__ sg_g,
    const float* __restrict__ ws,
    const float* __restrict__ wn, const float* __restrict__ wd,
    const float* __restrict__ outw, const float* __restrict__ outb,
    float* __restrict__ out, int img0, int nimg) {
    const float* par = ws + OFF_PAR;
    int tid = threadIdx.x, wave = tid >> 6, lane = tid & 63;
    int li = lane / 19, j = lane - li * 19;
    if (li > 2) { li = 2; j = 18; }
    int il = blockIdx.x * 12 + wave * 3 + li;
    int ilc = il < nimg ? il : nimg - 1;

    const float L2E = 1.44269504f;
    float aj[19], bj[19], wpj[19], wpej[19];
    #pragma unroll
    for (int i = 0; i < 19; i++) {
        float mu = mu_g[i * 19 + j];
        float sg = sg_g[i * 19 + j];
        aj[i] = -sg * L2E;
        bj[i] = mu * sg * L2E;
        wpj[i] = par[P_WP + i * 19 + j];
        wpej[i] = par[P_WPE + i * 19 + j];
    }
    float cmt = par[P_CMT + j], gl = par[P_GL + j], glvl = par[P_GLVL + j];
    float v = 0.f;
    long base0 = (long)ilc * 608 + j;
    float wns = wn[base0], wds = wd[base0];
    int lbase = li * 19;
    for (int t = 0; t < 32; t++) {
        float wns_n = 0.f, wds_n = 0.f;
        if (t < 31) {
            long basen = base0 + (t + 1) * 19;
            wns_n = wn[basen];
            wds_n = wd[basen];
        }
        #pragma unroll 1
        for (int u = 0; u < 6; u++) {
            float vi[19];
            #pragma unroll
            for (int i = 0; i < 19; i++) vi[i] = __shfl(v, lbase + i, 64);
            float sg[19];
            #pragma unroll
            for (int i = 0; i < 19; i++)
                sg[i] = __builtin_amdgcn_exp2f(fmaf(vi[i], aj[i], bj[i]));
            float n0 = 0.f, n1 = 0.f, d0 = 0.f, d1 = 0.f;
            #pragma unroll
            for (int i = 0; i < 19; i++) {
                float s = __builtin_amdgcn_rcpf(1.0f + sg[i]);
                if (i & 1) { n1 = fmaf(wpej[i], s, n1); d1 = fmaf(wpj[i], s, d1); }
                else       { n0 = fmaf(wpej[i], s, n0); d0 = fmaf(wpj[i], s, d0); }
            }
            float num = fmaf(cmt, v, glvl) + wns + (n0 + n1);
            float den = cmt + gl + wds + (d0 + d1);
            v = num * __builtin_amdgcn_rcpf(den + 1e-8f);
        }
        wns = wns_n; wds = wds_n;
    }
    if (j < 2 && il < nimg && lane < 57)
        out[(long)(img0 + il) * 2 + j] = fmaf(v, outw[j], outb[j]);
}

extern "C" void kernel_launch(void* const* d_in, const int* in_sizes, int n_in,
                              void* d_out, int out_size, void* d_ws, size_t ws_size,
                              hipStream_t stream) {
    const float* x    = (const float*)d_in[0];
    const float* w1   = (const float*)d_in[1];
    const float* b1   = (const float*)d_in[2];
    const float* w2   = (const float*)d_in[3];
    const float* b2   = (const float*)d_in[4];
    const float* g2   = (const float*)d_in[5];
    const float* be2  = (const float*)d_in[6];
    const float* m2   = (const float*)d_in[7];
    const float* v2   = (const float*)d_in[8];
    const float* w3   = (const float*)d_in[9];
    const float* b3   = (const float*)d_in[10];
    const float* w4   = (const float*)d_in[11];
    const float* b4   = (const float*)d_in[12];
    const float* g4   = (const float*)d_in[13];
    const float* be4  = (const float*)d_in[14];
    const float* m4   = (const float*)d_in[15];
    const float* v4   = (const float*)d_in[16];
    const float* inw  = (const float*)d_in[17];
    const float* inb  = (const float*)d_in[18];
    const float* smu  = (const float*)d_in[19];
    const float* ssig = (const float*)d_in[20];
    const float* sw   = (const float*)d_in[21];
    const float* serv = (const float*)d_in[22];
    const float* smk  = (const float*)d_in[23];
    const float* mu_  = (const float*)d_in[24];
    const float* sig_ = (const float*)d_in[25];
    const float* w_   = (const float*)d_in[26];
    const float* erev = (const float*)d_in[27];
    const float* mask = (const float*)d_in[28];
    const float* glk  = (const float*)d_in[29];
    const float* vlk  = (const float*)d_in[30];
    const float* cm   = (const float*)d_in[31];
    const float* outw = (const float*)d_in[32];
    const float* outb = (const float*)d_in[33];
    float* ws = (float*)d_ws;

    k_prep<<<64, 256, 0, stream>>>(w2, w3, w4, sw, serv, smk, w_, erev, mask,
                                   glk, vlk, cm, b2, g2, be2, m2, v2,
                                   b4, g4, be4, m4, v4, ws);

    // auto-size batch chunk: per-image = h2(6272 u32) + wn/wd(1216 f32)
    long avail = (long)(ws_size / 4) - OFF_DYN;
    long per = 6272 + 1216;
    int chunk = (int)(avail / per);
    if (chunk > BATCH) chunk = BATCH;
    if (chunk < 2) chunk = 2;

    float* wnp = ws + OFF_DYN;
    float* wdp = wnp + (long)chunk * 608;
    unsigned* h2 = (unsigned*)(wdp + (long)chunk * 608);

    for (int c0 = 0; c0 < BATCH; c0 += chunk) {
        int n = (BATCH - c0 < chunk) ? (BATCH - c0) : chunk;
        k_conv12<<<n, 512, 0, stream>>>(x + (long)c0 * 784, w1, b1, ws, h2);
        k_conv34s<<<(n + 1) / 2, 256, 0, stream>>>(h2, b3, inw, inb, smu, ssig, ws,
                                                   wnp, wdp, n);
        k_ltc<<<(n + 11) / 12, 256, 0, stream>>>(mu_, sig_, ws, wnp, wdp, outw, outb,
                                                 (float*)d_out, c0, n);
    }
}